// Round 1
// baseline (3084.986 us; speedup 1.0000x reference)
//
#include <hip/hip_runtime.h>
#include <hip/hip_bf16.h>
#include <utility>

#define CS 64  // scan chunk size

// ---------------- patch embed: conv 4x4 stride 4, in 1x256x256 -> 64x64x64
__global__ void k_patch_embed(const float* __restrict__ E0, const float* __restrict__ w,
                              const float* __restrict__ b, float* __restrict__ out) {
  int idx = blockIdx.x * blockDim.x + threadIdx.x;
  if (idx >= 64 * 64 * 64) return;
  int c = idx >> 12;
  int p = idx & 4095;
  int oh = p >> 6, ow = p & 63;
  const float* src = E0 + (oh * 4) * 256 + ow * 4;
  const float* wc = w + c * 16;
  float acc = b[c];
#pragma unroll
  for (int i = 0; i < 4; i++)
#pragma unroll
    for (int j = 0; j < 4; j++) acc += src[i * 256 + j] * wc[i * 4 + j];
  out[idx] = acc;
}

// ---------------- ln2d over C=64 channels (one wave per pixel)
__global__ void k_ln2d64(const float* __restrict__ x, const float* __restrict__ g,
                         const float* __restrict__ b, float* __restrict__ y, int HW) {
  int p = blockIdx.x;
  int c = threadIdx.x;
  float v = x[c * HW + p];
  float s = v, s2 = v * v;
#pragma unroll
  for (int m = 32; m >= 1; m >>= 1) {
    s += __shfl_xor(s, m, 64);
    s2 += __shfl_xor(s2, m, 64);
  }
  float mu = s * (1.f / 64.f);
  float var = s2 * (1.f / 64.f) - mu * mu;
  float rstd = rsqrtf(var + 1e-6f);
  y[c * HW + p] = (v - mu) * rstd * g[c] + b[c];
}

// ---------------- fused ln2d(C=64) + input projection (64 -> 256), split xc/z
__global__ void k_lnproj(const float* __restrict__ x, const float* __restrict__ g,
                         const float* __restrict__ b, const float* __restrict__ w,
                         float* __restrict__ xc, float* __restrict__ z, int HW) {
  int p = blockIdx.x;
  int t = threadIdx.x;  // 256 threads
  __shared__ float hsh[64];
  if (t < 64) {
    float v = x[t * HW + p];
    float s = v, s2 = v * v;
#pragma unroll
    for (int m = 32; m >= 1; m >>= 1) {
      s += __shfl_xor(s, m, 64);
      s2 += __shfl_xor(s2, m, 64);
    }
    float mu = s * (1.f / 64.f);
    float var = s2 * (1.f / 64.f) - mu * mu;
    float rstd = rsqrtf(var + 1e-6f);
    hsh[t] = (v - mu) * rstd * g[t] + b[t];
  }
  __syncthreads();
  float acc = 0.f;
  const float* wp = w + t;  // w[c*256 + t]
#pragma unroll
  for (int c = 0; c < 64; c++) acc += hsh[c] * wp[c * 256];
  if (t < 128)
    xc[t * HW + p] = acc;
  else
    z[(t - 128) * HW + p] = acc;
}

// ---------------- depthwise conv 3x3 pad 1 + silu (DI=128)
__global__ void k_dwconv(const float* __restrict__ xc, const float* __restrict__ w,
                         const float* __restrict__ b, float* __restrict__ out, int H, int lgH) {
  int HW = H * H;
  int idx = blockIdx.x * blockDim.x + threadIdx.x;
  if (idx >= 128 * HW) return;
  int d = idx >> (2 * lgH);
  int p = idx & (HW - 1);
  int ph = p >> lgH, pw = p & (H - 1);
  const float* wp = w + d * 9;
  const float* xb = xc + d * HW;
  float acc = b[d];
#pragma unroll
  for (int i = 0; i < 3; i++) {
    int ih = ph + i - 1;
    if (ih < 0 || ih >= H) continue;
#pragma unroll
    for (int j = 0; j < 3; j++) {
      int iw = pw + j - 1;
      if (iw < 0 || iw >= H) continue;
      acc += xb[ih * H + iw] * wp[i * 3 + j];
    }
  }
  out[idx] = acc / (1.f + expf(-acc));
}

// ---------------- x-projection (36 outputs per (k,l)) + delta=softplus(...)
__global__ void k_xproj(const float* __restrict__ xcs, const float* __restrict__ xpw,
                        const float* __restrict__ dtw, const float* __restrict__ dtb,
                        float* __restrict__ delta, float* __restrict__ Bs,
                        float* __restrict__ Cs, int H, int lgH) {
  int L = H * H;
  int l = blockIdx.x;
  int k = blockIdx.y;
  int d = threadIdx.x;  // 128
  int lm = (k & 2) ? (L - 1 - l) : l;
  int idx = (k & 1) ? ((lm & (H - 1)) * H + (lm >> lgH)) : lm;
  __shared__ float xs[128];
  __shared__ float r4[4];
  xs[d] = xcs[d * L + idx];
  __syncthreads();
  if (d < 36) {
    const float* wr = xpw + (k * 36 + d) * 128;
    float acc = 0.f;
#pragma unroll
    for (int c = 0; c < 128; c++) acc += xs[c] * wr[c];
    if (d < 4)
      r4[d] = acc;
    else if (d < 20)
      Bs[(k * 16 + (d - 4)) * L + l] = acc;
    else
      Cs[(k * 16 + (d - 20)) * L + l] = acc;
  }
  __syncthreads();
  float dt = dtb[k * 128 + d];
  const float* wd = dtw + (k * 128 + d) * 4;
  dt += r4[0] * wd[0] + r4[1] * wd[1] + r4[2] * wd[2] + r4[3] * wd[3];
  float sp = fmaxf(dt, 0.f) + log1pf(expf(-fabsf(dt)));
  delta[((size_t)(k * 128 + d)) * L + l] = sp;
}

// ---------------- scan phase A: per-chunk local scan (init 0) + chunk decay
__global__ void k_scanA(const float* __restrict__ xcs, const float* __restrict__ delta,
                        const float* __restrict__ Bs, const float* __restrict__ A_log,
                        float* __restrict__ hloc, float* __restrict__ pA, int H, int lgH,
                        int nc) {
  int L = H * H;
  int c = blockIdx.x;
  int k = blockIdx.y;
  int d = threadIdx.x;  // 128
  float A[16], h[16];
#pragma unroll
  for (int n = 0; n < 16; n++) {
    A[n] = -expf(A_log[(k * 128 + d) * 16 + n]);
    h[n] = 0.f;
  }
  float sumdt = 0.f;
  const float* dp = delta + (size_t)(k * 128 + d) * L;
  const float* up = xcs + (size_t)d * L;
  int l0 = c * CS;
  for (int l = l0; l < l0 + CS; l++) {
    int lm = (k & 2) ? (L - 1 - l) : l;
    int idx = (k & 1) ? ((lm & (H - 1)) * H + (lm >> lgH)) : lm;
    float u = up[idx];
    float dt = dp[l];
    float du = dt * u;
    sumdt += dt;
#pragma unroll
    for (int n = 0; n < 16; n++) {
      float dA = expf(dt * A[n]);
      h[n] = dA * h[n] + Bs[(k * 16 + n) * L + l] * du;
    }
  }
  size_t base = (((size_t)(k * 128 + d)) * nc + c) * 16;
#pragma unroll
  for (int n = 0; n < 16; n++) {
    hloc[base + n] = h[n];
    pA[base + n] = expf(A[n] * sumdt);
  }
}

// ---------------- scan phase B: stitch chunk summaries -> per-chunk init state
__global__ void k_scanB(const float* __restrict__ hloc, const float* __restrict__ pA,
                        float* __restrict__ hinit, int nc) {
  int k = blockIdx.x;
  int d = threadIdx.x;
  float h[16];
#pragma unroll
  for (int n = 0; n < 16; n++) h[n] = 0.f;
  size_t rb = ((size_t)(k * 128 + d)) * nc;
  for (int c = 0; c < nc; c++) {
    size_t base = (rb + c) * 16;
#pragma unroll
    for (int n = 0; n < 16; n++) {
      hinit[base + n] = h[n];
      h[n] = pA[base + n] * h[n] + hloc[base + n];
    }
  }
}

// ---------------- scan phase C: rescan with correct init, emit y
__global__ void k_scanC(const float* __restrict__ xcs, const float* __restrict__ delta,
                        const float* __restrict__ Bs, const float* __restrict__ Cs,
                        const float* __restrict__ A_log, const float* __restrict__ Dp,
                        const float* __restrict__ hinit, float* __restrict__ ys, int H,
                        int lgH, int nc) {
  int L = H * H;
  int c = blockIdx.x;
  int k = blockIdx.y;
  int d = threadIdx.x;
  float A[16], h[16];
  size_t base = (((size_t)(k * 128 + d)) * nc + c) * 16;
#pragma unroll
  for (int n = 0; n < 16; n++) {
    A[n] = -expf(A_log[(k * 128 + d) * 16 + n]);
    h[n] = hinit[base + n];
  }
  float Dv = Dp[k * 128 + d];
  const float* dp = delta + (size_t)(k * 128 + d) * L;
  const float* up = xcs + (size_t)d * L;
  float* yp = ys + (size_t)(k * 128 + d) * L;
  int l0 = c * CS;
  for (int l = l0; l < l0 + CS; l++) {
    int lm = (k & 2) ? (L - 1 - l) : l;
    int idx = (k & 1) ? ((lm & (H - 1)) * H + (lm >> lgH)) : lm;
    float u = up[idx];
    float dt = dp[l];
    float du = dt * u;
    float y = 0.f;
#pragma unroll
    for (int n = 0; n < 16; n++) {
      float dA = expf(dt * A[n]);
      h[n] = dA * h[n] + Bs[(k * 16 + n) * L + l] * du;
      y += h[n] * Cs[(k * 16 + n) * L + l];
    }
    yp[l] = y + Dv * u;
  }
}

// ---------------- combine 4 directions + LN(128) + silu(z) gate + out proj + residual
__global__ void k_combine(const float* __restrict__ ys, const float* __restrict__ z,
                          const float* __restrict__ xin, const float* __restrict__ ong,
                          const float* __restrict__ onb, const float* __restrict__ outw,
                          float* __restrict__ xout, int H, int lgH) {
  int L = H * H;
  int p = blockIdx.x;
  int d = threadIdx.x;  // 128
  int ph = p >> lgH, pw = p & (H - 1);
  int l1 = pw * H + ph;
  float yv = ys[(size_t)(0 * 128 + d) * L + p] + ys[(size_t)(1 * 128 + d) * L + l1] +
             ys[(size_t)(2 * 128 + d) * L + (L - 1 - p)] +
             ys[(size_t)(3 * 128 + d) * L + (L - 1 - l1)];
  float s = yv, s2 = yv * yv;
#pragma unroll
  for (int m = 32; m >= 1; m >>= 1) {
    s += __shfl_xor(s, m, 64);
    s2 += __shfl_xor(s2, m, 64);
  }
  __shared__ float ws1[2], ws2[2];
  int wid = d >> 6;
  if ((d & 63) == 0) {
    ws1[wid] = s;
    ws2[wid] = s2;
  }
  __syncthreads();
  float tot = ws1[0] + ws1[1], tot2 = ws2[0] + ws2[1];
  float mu = tot * (1.f / 128.f);
  float var = tot2 * (1.f / 128.f) - mu * mu;
  float rstd = rsqrtf(var + 1e-6f);
  float zt = z[(size_t)d * L + p];
  float yt = ((yv - mu) * rstd * ong[d] + onb[d]) * (zt / (1.f + expf(-zt)));
  __shared__ float ysm[128];
  ysm[d] = yt;
  __syncthreads();
  if (d < 64) {
    float acc = xin[(size_t)d * L + p];
#pragma unroll
    for (int q = 0; q < 128; q++) acc += ysm[q] * outw[q * 64 + d];
    xout[(size_t)d * L + p] = acc;
  }
}

// ---------------- generic 64->64 conv3x3 (stride 1 or 2), optional silu + skip
__global__ void k_conv3x3(const float* __restrict__ x, const float* __restrict__ w,
                          const float* __restrict__ b, const float* __restrict__ skip,
                          float* __restrict__ out, int Hin, int Win, int Hout, int Wout,
                          int stride, int do_silu) {
  int idx = blockIdx.x * blockDim.x + threadIdx.x;
  int HWo = Hout * Wout;
  if (idx >= 64 * HWo) return;
  int co = idx / HWo;
  int p = idx - co * HWo;
  int oh = p / Wout, ow = p - (p / Wout) * Wout;
  float acc = b[co];
  const float* wb = w + co * 64 * 9;
  for (int ci = 0; ci < 64; ci++) {
    const float* xb = x + (size_t)ci * Hin * Win;
    const float* wc = wb + ci * 9;
#pragma unroll
    for (int i = 0; i < 3; i++) {
      int ih = oh * stride + i - 1;
      if (ih < 0 || ih >= Hin) continue;
#pragma unroll
      for (int j = 0; j < 3; j++) {
        int iw = ow * stride + j - 1;
        if (iw < 0 || iw >= Win) continue;
        acc += xb[ih * Win + iw] * wc[i * 3 + j];
      }
    }
  }
  if (do_silu) acc = acc / (1.f + expf(-acc));
  if (skip) acc += skip[idx];
  out[idx] = acc;
}

// ---------------- bilinear resize (half-pixel centers, edge clamp == jax upsample)
__global__ void k_resize(const float* __restrict__ x, float* __restrict__ out, int Hin,
                         int Win, int Hout, int Wout, float inv_scale) {
  int idx = blockIdx.x * blockDim.x + threadIdx.x;
  int HWo = Hout * Wout;
  if (idx >= 64 * HWo) return;
  int c = idx / HWo;
  int p = idx - c * HWo;
  int oh = p / Wout, ow = p - (p / Wout) * Wout;
  float sh = (oh + 0.5f) * inv_scale - 0.5f;
  float sw = (ow + 0.5f) * inv_scale - 0.5f;
  int h0 = (int)floorf(sh);
  float fh = sh - h0;
  int w0 = (int)floorf(sw);
  float fw = sw - w0;
  int h0c = min(max(h0, 0), Hin - 1), h1c = min(max(h0 + 1, 0), Hin - 1);
  int w0c = min(max(w0, 0), Win - 1), w1c = min(max(w0 + 1, 0), Win - 1);
  const float* xb = x + (size_t)c * Hin * Win;
  float v = (1.f - fh) * ((1.f - fw) * xb[h0c * Win + w0c] + fw * xb[h0c * Win + w1c]) +
            fh * ((1.f - fw) * xb[h1c * Win + w0c] + fw * xb[h1c * Win + w1c]);
  out[idx] = v;
}

extern "C" void kernel_launch(void* const* d_in, const int* in_sizes, int n_in, void* d_out,
                              int out_size, void* d_ws, size_t ws_size, hipStream_t stream) {
  const float* E0 = (const float*)d_in[0];
  const float* pe_w = (const float*)d_in[1];
  const float* pe_b = (const float*)d_in[2];
  const float* pe_lg = (const float*)d_in[3];
  const float* pe_lb = (const float*)d_in[4];
  const float* ln_g = (const float*)d_in[5];
  const float* ln_b = (const float*)d_in[6];
  const float* in_w = (const float*)d_in[7];
  const float* cv_w = (const float*)d_in[8];
  const float* cv_b = (const float*)d_in[9];
  const float* xp_w = (const float*)d_in[10];
  const float* dt_w = (const float*)d_in[11];
  const float* dt_b = (const float*)d_in[12];
  const float* A_log = (const float*)d_in[13];
  const float* Dp = (const float*)d_in[14];
  const float* on_g = (const float*)d_in[15];
  const float* on_b = (const float*)d_in[16];
  const float* out_pw = (const float*)d_in[17];
  const float* dn_w = (const float*)d_in[18];
  const float* dn_b = (const float*)d_in[19];
  const float* dn_g = (const float*)d_in[20];
  const float* dn_lb = (const float*)d_in[21];
  const float* up_w = (const float*)d_in[22];
  const float* up_b = (const float*)d_in[23];
  const float* oc_w = (const float*)d_in[24];
  const float* oc_b = (const float*)d_in[25];

  float* ws = (float*)d_ws;
  size_t off = 0;
  auto alloc = [&](size_t n) {
    float* p = ws + off;
    off += n;
    return p;
  };
  float* xA = alloc(64 * 4096);
  float* xB = alloc(64 * 4096);
  float* xc = alloc(128 * 4096);
  float* zb = alloc(128 * 4096);
  float* xcs = alloc(128 * 4096);
  float* dlt = alloc((size_t)4 * 128 * 4096);
  float* Bsb = alloc(4 * 16 * 4096);
  float* Csb = alloc(4 * 16 * 4096);
  float* ysb = alloc((size_t)4 * 128 * 4096);
  float* hloc = alloc(4 * 128 * 64 * 16);
  float* pAb = alloc(4 * 128 * 64 * 16);
  float* hin = alloc(4 * 128 * 64 * 16);
  float* sk0 = alloc(64 * 4096);
  float* sk1 = alloc(64 * 1024);
  float* sk2 = alloc(64 * 256);
  float* sk3 = alloc(64 * 64);
  float* tmpR = alloc((size_t)64 * 256 * 256);

  // patch embed + first LN
  k_patch_embed<<<(64 * 4096 + 255) / 256, 256, 0, stream>>>(E0, pe_w, pe_b, xA);
  k_ln2d64<<<4096, 64, 0, stream>>>(xA, pe_lg, pe_lb, xB, 4096);
  float* x = xB;
  float* xalt = xA;

  int Hs[4] = {64, 32, 16, 8};
  int lgHs[4] = {6, 5, 4, 3};
  float* skips[4] = {sk0, sk1, sk2, sk3};
  int cur = 0;

  auto vss = [&](int H, int lgH) {
    int L = H * H;
    int nc = L >> 6;  // chunks of CS=64
    k_lnproj<<<L, 256, 0, stream>>>(x, ln_g + cur * 64, ln_b + cur * 64,
                                    in_w + (size_t)cur * 64 * 256, xc, zb, L);
    k_dwconv<<<(128 * L + 255) / 256, 256, 0, stream>>>(xc, cv_w + (size_t)cur * 128 * 9,
                                                        cv_b + cur * 128, xcs, H, lgH);
    dim3 gx(L, 4);
    k_xproj<<<gx, 128, 0, stream>>>(xcs, xp_w + (size_t)cur * 4 * 36 * 128,
                                    dt_w + (size_t)cur * 4 * 128 * 4, dt_b + cur * 4 * 128,
                                    dlt, Bsb, Csb, H, lgH);
    dim3 ga(nc, 4);
    k_scanA<<<ga, 128, 0, stream>>>(xcs, dlt, Bsb, A_log + (size_t)cur * 4 * 128 * 16, hloc,
                                    pAb, H, lgH, nc);
    k_scanB<<<4, 128, 0, stream>>>(hloc, pAb, hin, nc);
    k_scanC<<<ga, 128, 0, stream>>>(xcs, dlt, Bsb, Csb, A_log + (size_t)cur * 4 * 128 * 16,
                                    Dp + cur * 4 * 128, hin, ysb, H, lgH, nc);
    k_combine<<<L, 128, 0, stream>>>(ysb, zb, x, on_g + cur * 128, on_b + cur * 128,
                                     out_pw + (size_t)cur * 128 * 64, xalt, H, lgH);
    std::swap(x, xalt);
    cur++;
  };

  for (int i = 0; i < 4; i++) {
    int H = Hs[i], lgH = lgHs[i];
    vss(H, lgH);
    vss(H, lgH);
    hipMemcpyAsync(skips[i], x, (size_t)64 * H * H * sizeof(float),
                   hipMemcpyDeviceToDevice, stream);
    if (i < 3) {
      int Ho = H / 2;
      k_conv3x3<<<(64 * Ho * Ho + 255) / 256, 256, 0, stream>>>(
          x, dn_w + (size_t)i * 64 * 64 * 9, dn_b + i * 64, nullptr, xalt, H, H, Ho, Ho, 2, 0);
      k_ln2d64<<<Ho * Ho, 64, 0, stream>>>(xalt, dn_g + i * 64, dn_lb + i * 64, x, Ho * Ho);
    }
  }

  // up path: x at 8x8
  for (int i = 0; i < 3; i++) {
    int Hin = 8 << i, Ho = Hin * 2;
    k_resize<<<(64 * Ho * Ho + 255) / 256, 256, 0, stream>>>(x, tmpR, Hin, Hin, Ho, Ho, 0.5f);
    k_conv3x3<<<(64 * Ho * Ho + 255) / 256, 256, 0, stream>>>(
        tmpR, up_w + (size_t)i * 64 * 64 * 9, up_b + i * 64, skips[2 - i], xalt, Ho, Ho, Ho,
        Ho, 1, 1);
    std::swap(x, xalt);
  }

  // final: x at 64x64 -> resize x4 -> conv+silu -> out
  k_resize<<<(64 * 256 * 256 + 255) / 256, 256, 0, stream>>>(x, tmpR, 64, 64, 256, 256, 0.25f);
  k_conv3x3<<<(64 * 256 * 256 + 255) / 256, 256, 0, stream>>>(tmpR, oc_w, oc_b, nullptr,
                                                              (float*)d_out, 256, 256, 256,
                                                              256, 1, 1);
}

// Round 2
// 1769.396 us; speedup vs baseline: 1.7435x; 1.7435x over previous
//
#include <hip/hip_runtime.h>
#include <hip/hip_bf16.h>
#include <utility>

#define CS 64   // scan chunk size
#define CIC 8   // conv input-channel chunk

// ---------------- patch embed: conv 4x4 stride 4, in 1x256x256 -> 64x64x64
__global__ void k_patch_embed(const float* __restrict__ E0, const float* __restrict__ w,
                              const float* __restrict__ b, float* __restrict__ out) {
  int idx = blockIdx.x * blockDim.x + threadIdx.x;
  if (idx >= 64 * 64 * 64) return;
  int c = idx >> 12;
  int p = idx & 4095;
  int oh = p >> 6, ow = p & 63;
  const float* src = E0 + (oh * 4) * 256 + ow * 4;
  const float* wc = w + c * 16;
  float acc = b[c];
#pragma unroll
  for (int i = 0; i < 4; i++)
#pragma unroll
    for (int j = 0; j < 4; j++) acc += src[i * 256 + j] * wc[i * 4 + j];
  out[idx] = acc;
}

// ---------------- ln2d over C=64 channels (one wave per pixel)
__global__ void k_ln2d64(const float* __restrict__ x, const float* __restrict__ g,
                         const float* __restrict__ b, float* __restrict__ y, int HW) {
  int p = blockIdx.x;
  int c = threadIdx.x;
  float v = x[c * HW + p];
  float s = v, s2 = v * v;
#pragma unroll
  for (int m = 32; m >= 1; m >>= 1) {
    s += __shfl_xor(s, m, 64);
    s2 += __shfl_xor(s2, m, 64);
  }
  float mu = s * (1.f / 64.f);
  float var = s2 * (1.f / 64.f) - mu * mu;
  float rstd = rsqrtf(var + 1e-6f);
  y[c * HW + p] = (v - mu) * rstd * g[c] + b[c];
}

// ---------------- fused ln2d(C=64) + input projection (64 -> 256), split xc/z
// xc, z output layout: [L][128] pixel-major
__global__ void k_lnproj(const float* __restrict__ x, const float* __restrict__ g,
                         const float* __restrict__ b, const float* __restrict__ w,
                         float* __restrict__ xc, float* __restrict__ z, int HW) {
  int p = blockIdx.x;
  int t = threadIdx.x;  // 256 threads
  __shared__ float hsh[64];
  if (t < 64) {
    float v = x[t * HW + p];
    float s = v, s2 = v * v;
#pragma unroll
    for (int m = 32; m >= 1; m >>= 1) {
      s += __shfl_xor(s, m, 64);
      s2 += __shfl_xor(s2, m, 64);
    }
    float mu = s * (1.f / 64.f);
    float var = s2 * (1.f / 64.f) - mu * mu;
    float rstd = rsqrtf(var + 1e-6f);
    hsh[t] = (v - mu) * rstd * g[t] + b[t];
  }
  __syncthreads();
  float acc = 0.f;
  const float* wp = w + t;  // w[c*256 + t]
#pragma unroll
  for (int c = 0; c < 64; c++) acc += hsh[c] * wp[c * 256];
  if (t < 128)
    xc[(size_t)p * 128 + t] = acc;
  else
    z[(size_t)p * 128 + (t - 128)] = acc;
}

// ---------------- depthwise conv 3x3 pad 1 + silu; pixel-major [L][128]
__global__ void k_dwconv(const float* __restrict__ xc, const float* __restrict__ w,
                         const float* __restrict__ b, float* __restrict__ out, int H, int lgH) {
  int HW = H * H;
  int idx = blockIdx.x * blockDim.x + threadIdx.x;
  if (idx >= 128 * HW) return;
  int p = idx >> 7;
  int d = idx & 127;
  int ph = p >> lgH, pw = p & (H - 1);
  const float* wp = w + d * 9;
  float acc = b[d];
#pragma unroll
  for (int i = 0; i < 3; i++) {
    int ih = ph + i - 1;
    if (ih < 0 || ih >= H) continue;
#pragma unroll
    for (int j = 0; j < 3; j++) {
      int iw = pw + j - 1;
      if (iw < 0 || iw >= H) continue;
      acc += xc[(size_t)(ih * H + iw) * 128 + d] * wp[i * 3 + j];
    }
  }
  out[(size_t)p * 128 + d] = acc / (1.f + __expf(-acc));
}

// ---------------- x-projection + delta=softplus(...)
// xcs: [L][128]; delta out: [k][L][128]; Bs/Cs out: [k][L][16]
__global__ void k_xproj(const float* __restrict__ xcs, const float* __restrict__ xpw,
                        const float* __restrict__ dtw, const float* __restrict__ dtb,
                        float* __restrict__ delta, float* __restrict__ Bs,
                        float* __restrict__ Cs, int H, int lgH) {
  int L = H * H;
  int l = blockIdx.x;
  int k = blockIdx.y;
  int t = threadIdx.x;  // 256
  int lm = (k & 2) ? (L - 1 - l) : l;
  int idx = (k & 1) ? ((lm & (H - 1)) * H + (lm >> lgH)) : lm;
  __shared__ float xs[128];
  __shared__ float part[36][4];
  __shared__ float r4[4];
  if (t < 128) xs[t] = xcs[(size_t)idx * 128 + t];
  __syncthreads();
  if (t < 144) {
    int r = t >> 2, q = t & 3;
    const float* wr = xpw + (k * 36 + r) * 128 + q * 32;
    const float* xp = xs + q * 32;
    float acc = 0.f;
#pragma unroll
    for (int c = 0; c < 32; c++) acc += xp[c] * wr[c];
    part[r][q] = acc;
  }
  __syncthreads();
  if (t < 36) {
    float acc = part[t][0] + part[t][1] + part[t][2] + part[t][3];
    if (t < 4)
      r4[t] = acc;
    else if (t < 20)
      Bs[((size_t)k * L + l) * 16 + (t - 4)] = acc;
    else
      Cs[((size_t)k * L + l) * 16 + (t - 20)] = acc;
  }
  __syncthreads();
  if (t < 128) {
    float dt = dtb[k * 128 + t];
    const float* wd = dtw + (k * 128 + t) * 4;
    dt += r4[0] * wd[0] + r4[1] * wd[1] + r4[2] * wd[2] + r4[3] * wd[3];
    float sp = fmaxf(dt, 0.f) + log1pf(__expf(-fabsf(dt)));
    delta[((size_t)k * L + l) * 128 + t] = sp;
  }
}

// ---------------- scan phase A: per-chunk local scan (init 0) + chunk decay
__global__ void k_scanA(const float* __restrict__ xcs, const float* __restrict__ delta,
                        const float* __restrict__ Bs, const float* __restrict__ A_log,
                        float* __restrict__ hloc, float* __restrict__ pA, int H, int lgH,
                        int nc) {
  int L = H * H;
  int c = blockIdx.x;
  int k = blockIdx.y;
  int d = threadIdx.x;  // 128
  float A[16], h[16];
#pragma unroll
  for (int n = 0; n < 16; n++) {
    A[n] = -expf(A_log[(k * 128 + d) * 16 + n]);
    h[n] = 0.f;
  }
  float sumdt = 0.f;
  int l0 = c * CS;
  for (int l = l0; l < l0 + CS; l++) {
    int lm = (k & 2) ? (L - 1 - l) : l;
    int idx = (k & 1) ? ((lm & (H - 1)) * H + (lm >> lgH)) : lm;
    float u = xcs[(size_t)idx * 128 + d];
    float dt = delta[((size_t)k * L + l) * 128 + d];
    float du = dt * u;
    sumdt += dt;
    const float4* bp = (const float4*)(Bs + ((size_t)k * L + l) * 16);
    float4 B0 = bp[0], B1 = bp[1], B2 = bp[2], B3 = bp[3];
    float Bv[16] = {B0.x, B0.y, B0.z, B0.w, B1.x, B1.y, B1.z, B1.w,
                    B2.x, B2.y, B2.z, B2.w, B3.x, B3.y, B3.z, B3.w};
#pragma unroll
    for (int n = 0; n < 16; n++) h[n] = __expf(dt * A[n]) * h[n] + Bv[n] * du;
  }
  size_t base = (((size_t)(k * 128 + d)) * nc + c) * 16;
#pragma unroll
  for (int n = 0; n < 16; n++) {
    hloc[base + n] = h[n];
    pA[base + n] = __expf(A[n] * sumdt);
  }
}

// ---------------- scan phase B: stitch chunk summaries -> per-chunk init state
__global__ void k_scanB(const float* __restrict__ hloc, const float* __restrict__ pA,
                        float* __restrict__ hinit, int nc) {
  int k = blockIdx.x;
  int d = threadIdx.x;
  float4 h0 = {0, 0, 0, 0}, h1 = {0, 0, 0, 0}, h2 = {0, 0, 0, 0}, h3 = {0, 0, 0, 0};
  size_t rb = ((size_t)(k * 128 + d)) * nc;
  const float4* hp = (const float4*)(hloc + rb * 16);
  const float4* pp = (const float4*)(pA + rb * 16);
  float4* ho = (float4*)(hinit + rb * 16);
  for (int c = 0; c < nc; c++) {
    float4 a0 = pp[c * 4 + 0], a1 = pp[c * 4 + 1], a2 = pp[c * 4 + 2], a3 = pp[c * 4 + 3];
    float4 b0 = hp[c * 4 + 0], b1 = hp[c * 4 + 1], b2 = hp[c * 4 + 2], b3 = hp[c * 4 + 3];
    ho[c * 4 + 0] = h0;
    ho[c * 4 + 1] = h1;
    ho[c * 4 + 2] = h2;
    ho[c * 4 + 3] = h3;
    h0.x = a0.x * h0.x + b0.x; h0.y = a0.y * h0.y + b0.y;
    h0.z = a0.z * h0.z + b0.z; h0.w = a0.w * h0.w + b0.w;
    h1.x = a1.x * h1.x + b1.x; h1.y = a1.y * h1.y + b1.y;
    h1.z = a1.z * h1.z + b1.z; h1.w = a1.w * h1.w + b1.w;
    h2.x = a2.x * h2.x + b2.x; h2.y = a2.y * h2.y + b2.y;
    h2.z = a2.z * h2.z + b2.z; h2.w = a2.w * h2.w + b2.w;
    h3.x = a3.x * h3.x + b3.x; h3.y = a3.y * h3.y + b3.y;
    h3.z = a3.z * h3.z + b3.z; h3.w = a3.w * h3.w + b3.w;
  }
}

// ---------------- scan phase C: rescan with correct init, emit y; ys: [k][L][128]
__global__ void k_scanC(const float* __restrict__ xcs, const float* __restrict__ delta,
                        const float* __restrict__ Bs, const float* __restrict__ Cs,
                        const float* __restrict__ A_log, const float* __restrict__ Dp,
                        const float* __restrict__ hinit, float* __restrict__ ys, int H,
                        int lgH, int nc) {
  int L = H * H;
  int c = blockIdx.x;
  int k = blockIdx.y;
  int d = threadIdx.x;
  float A[16], h[16];
  size_t base = (((size_t)(k * 128 + d)) * nc + c) * 16;
#pragma unroll
  for (int n = 0; n < 16; n++) {
    A[n] = -expf(A_log[(k * 128 + d) * 16 + n]);
    h[n] = hinit[base + n];
  }
  float Dv = Dp[k * 128 + d];
  int l0 = c * CS;
  for (int l = l0; l < l0 + CS; l++) {
    int lm = (k & 2) ? (L - 1 - l) : l;
    int idx = (k & 1) ? ((lm & (H - 1)) * H + (lm >> lgH)) : lm;
    float u = xcs[(size_t)idx * 128 + d];
    float dt = delta[((size_t)k * L + l) * 128 + d];
    float du = dt * u;
    const float4* bp = (const float4*)(Bs + ((size_t)k * L + l) * 16);
    float4 B0 = bp[0], B1 = bp[1], B2 = bp[2], B3 = bp[3];
    float Bv[16] = {B0.x, B0.y, B0.z, B0.w, B1.x, B1.y, B1.z, B1.w,
                    B2.x, B2.y, B2.z, B2.w, B3.x, B3.y, B3.z, B3.w};
    const float4* cp = (const float4*)(Cs + ((size_t)k * L + l) * 16);
    float4 C0 = cp[0], C1 = cp[1], C2 = cp[2], C3 = cp[3];
    float Cv[16] = {C0.x, C0.y, C0.z, C0.w, C1.x, C1.y, C1.z, C1.w,
                    C2.x, C2.y, C2.z, C2.w, C3.x, C3.y, C3.z, C3.w};
    float y = 0.f;
#pragma unroll
    for (int n = 0; n < 16; n++) {
      h[n] = __expf(dt * A[n]) * h[n] + Bv[n] * du;
      y += h[n] * Cv[n];
    }
    ys[((size_t)k * L + l) * 128 + d] = y + Dv * u;
  }
}

// ---------------- combine 4 dirs + LN(128) + silu(z) gate + out proj + residual
// ys: [k][L][128]; z: [L][128]; xin/xout: [64][L]
__global__ void k_combine(const float* __restrict__ ys, const float* __restrict__ z,
                          const float* __restrict__ xin, const float* __restrict__ ong,
                          const float* __restrict__ onb, const float* __restrict__ outw,
                          float* __restrict__ xout, int H, int lgH) {
  int L = H * H;
  int p = blockIdx.x;
  int d = threadIdx.x;  // 128
  int ph = p >> lgH, pw = p & (H - 1);
  int l1 = pw * H + ph;
  float yv = ys[((size_t)0 * L + p) * 128 + d] + ys[((size_t)1 * L + l1) * 128 + d] +
             ys[((size_t)2 * L + (L - 1 - p)) * 128 + d] +
             ys[((size_t)3 * L + (L - 1 - l1)) * 128 + d];
  float s = yv, s2 = yv * yv;
#pragma unroll
  for (int m = 32; m >= 1; m >>= 1) {
    s += __shfl_xor(s, m, 64);
    s2 += __shfl_xor(s2, m, 64);
  }
  __shared__ float ws1[2], ws2[2];
  int wid = d >> 6;
  if ((d & 63) == 0) {
    ws1[wid] = s;
    ws2[wid] = s2;
  }
  __syncthreads();
  float tot = ws1[0] + ws1[1], tot2 = ws2[0] + ws2[1];
  float mu = tot * (1.f / 128.f);
  float var = tot2 * (1.f / 128.f) - mu * mu;
  float rstd = rsqrtf(var + 1e-6f);
  float zt = z[(size_t)p * 128 + d];
  float yt = ((yv - mu) * rstd * ong[d] + onb[d]) * (zt / (1.f + __expf(-zt)));
  __shared__ float ysm[128];
  ysm[d] = yt;
  __syncthreads();
  if (d < 64) {
    float acc = xin[(size_t)d * L + p];
#pragma unroll
    for (int q = 0; q < 128; q++) acc += ysm[q] * outw[q * 64 + d];
    xout[(size_t)d * L + p] = acc;
  }
}

// ---------------- stride-2 64->64 conv3x3 (small, down path only)
__global__ void k_conv3x3_s2(const float* __restrict__ x, const float* __restrict__ w,
                             const float* __restrict__ b, float* __restrict__ out, int Hin,
                             int Hout) {
  int idx = blockIdx.x * blockDim.x + threadIdx.x;
  int HWo = Hout * Hout;
  if (idx >= 64 * HWo) return;
  int co = idx / HWo;
  int p = idx - co * HWo;
  int oh = p / Hout, ow = p - (p / Hout) * Hout;
  float acc = b[co];
  const float* wb = w + co * 64 * 9;
  for (int ci = 0; ci < 64; ci++) {
    const float* xb = x + (size_t)ci * Hin * Hin;
    const float* wc = wb + ci * 9;
#pragma unroll
    for (int i = 0; i < 3; i++) {
      int ih = oh * 2 + i - 1;
      if (ih < 0 || ih >= Hin) continue;
#pragma unroll
      for (int j = 0; j < 3; j++) {
        int iw = ow * 2 + j - 1;
        if (iw < 0 || iw >= Hin) continue;
        acc += xb[ih * Hin + iw] * wc[i * 3 + j];
      }
    }
  }
  out[idx] = acc;
}

// ---------------- tiled stride-1 64->64 conv3x3 (+silu, +skip)
// 256 threads: thread = (px in 8x8 tile) x (co-group of 16); LDS-staged input+weights
__global__ void __launch_bounds__(256) k_conv3x3_s1(
    const float* __restrict__ x, const float* __restrict__ w, const float* __restrict__ b,
    const float* __restrict__ skip, float* __restrict__ out, int H, int W, int do_silu) {
  __shared__ __align__(16) float xsh[CIC][10][10];
  __shared__ __align__(16) float wsh[CIC][64][12];
  int t = threadIdx.x;
  int px = t & 63, cog = t >> 6;  // wave id == cog -> broadcast weight reads
  int tx = px & 7, ty = px >> 3;
  int ox = blockIdx.x * 8, oy = blockIdx.y * 8;
  float acc[16];
#pragma unroll
  for (int i = 0; i < 16; i++) acc[i] = b[cog * 16 + i];
  for (int cb = 0; cb < 64; cb += CIC) {
    for (int i = t; i < CIC * 100; i += 256) {
      int ci = i / 100;
      int r = i - ci * 100;
      int iy = r / 10, ix = r - (r / 10) * 10;
      int gy = oy + iy - 1, gx = ox + ix - 1;
      float v = 0.f;
      if (gy >= 0 && gy < H && gx >= 0 && gx < W) v = x[(size_t)(cb + ci) * H * W + gy * W + gx];
      xsh[ci][iy][ix] = v;
    }
    for (int i = t; i < CIC * 576; i += 256) {
      int ci = i / 576;
      int r = i - ci * 576;
      int co = r / 9, tap = r - (r / 9) * 9;
      wsh[ci][co][tap] = w[(size_t)co * 576 + (cb + ci) * 9 + tap];
    }
    __syncthreads();
#pragma unroll
    for (int ci = 0; ci < CIC; ci++) {
      float xv[9];
#pragma unroll
      for (int dy = 0; dy < 3; dy++)
#pragma unroll
        for (int dx = 0; dx < 3; dx++) xv[dy * 3 + dx] = xsh[ci][ty + dy][tx + dx];
#pragma unroll
      for (int i = 0; i < 16; i++) {
        int co = cog * 16 + i;
        float4 w0 = *(const float4*)&wsh[ci][co][0];
        float4 w1 = *(const float4*)&wsh[ci][co][4];
        float w8 = wsh[ci][co][8];
        acc[i] += xv[0] * w0.x + xv[1] * w0.y + xv[2] * w0.z + xv[3] * w0.w + xv[4] * w1.x +
                  xv[5] * w1.y + xv[6] * w1.z + xv[7] * w1.w + xv[8] * w8;
      }
    }
    __syncthreads();
  }
  int gp = (oy + ty) * W + ox + tx;
#pragma unroll
  for (int i = 0; i < 16; i++) {
    int co = cog * 16 + i;
    float a = acc[i];
    if (do_silu) a = a / (1.f + __expf(-a));
    if (skip) a += skip[(size_t)co * H * W + gp];
    out[(size_t)co * H * W + gp] = a;
  }
}

// ---------------- bilinear resize (half-pixel centers, edge clamp)
__global__ void k_resize(const float* __restrict__ x, float* __restrict__ out, int Hin,
                         int Win, int Hout, int Wout, float inv_scale) {
  int idx = blockIdx.x * blockDim.x + threadIdx.x;
  int HWo = Hout * Wout;
  if (idx >= 64 * HWo) return;
  int c = idx / HWo;
  int p = idx - c * HWo;
  int oh = p / Wout, ow = p - (p / Wout) * Wout;
  float sh = (oh + 0.5f) * inv_scale - 0.5f;
  float sw = (ow + 0.5f) * inv_scale - 0.5f;
  int h0 = (int)floorf(sh);
  float fh = sh - h0;
  int w0 = (int)floorf(sw);
  float fw = sw - w0;
  int h0c = min(max(h0, 0), Hin - 1), h1c = min(max(h0 + 1, 0), Hin - 1);
  int w0c = min(max(w0, 0), Win - 1), w1c = min(max(w0 + 1, 0), Win - 1);
  const float* xb = x + (size_t)c * Hin * Win;
  float v = (1.f - fh) * ((1.f - fw) * xb[h0c * Win + w0c] + fw * xb[h0c * Win + w1c]) +
            fh * ((1.f - fw) * xb[h1c * Win + w0c] + fw * xb[h1c * Win + w1c]);
  out[idx] = v;
}

extern "C" void kernel_launch(void* const* d_in, const int* in_sizes, int n_in, void* d_out,
                              int out_size, void* d_ws, size_t ws_size, hipStream_t stream) {
  const float* E0 = (const float*)d_in[0];
  const float* pe_w = (const float*)d_in[1];
  const float* pe_b = (const float*)d_in[2];
  const float* pe_lg = (const float*)d_in[3];
  const float* pe_lb = (const float*)d_in[4];
  const float* ln_g = (const float*)d_in[5];
  const float* ln_b = (const float*)d_in[6];
  const float* in_w = (const float*)d_in[7];
  const float* cv_w = (const float*)d_in[8];
  const float* cv_b = (const float*)d_in[9];
  const float* xp_w = (const float*)d_in[10];
  const float* dt_w = (const float*)d_in[11];
  const float* dt_b = (const float*)d_in[12];
  const float* A_log = (const float*)d_in[13];
  const float* Dp = (const float*)d_in[14];
  const float* on_g = (const float*)d_in[15];
  const float* on_b = (const float*)d_in[16];
  const float* out_pw = (const float*)d_in[17];
  const float* dn_w = (const float*)d_in[18];
  const float* dn_b = (const float*)d_in[19];
  const float* dn_g = (const float*)d_in[20];
  const float* dn_lb = (const float*)d_in[21];
  const float* up_w = (const float*)d_in[22];
  const float* up_b = (const float*)d_in[23];
  const float* oc_w = (const float*)d_in[24];
  const float* oc_b = (const float*)d_in[25];

  float* ws = (float*)d_ws;
  size_t off = 0;
  auto alloc = [&](size_t n) {
    float* p = ws + off;
    off += n;
    return p;
  };
  float* xA = alloc(64 * 4096);
  float* xB = alloc(64 * 4096);
  float* xc = alloc(128 * 4096);
  float* zb = alloc(128 * 4096);
  float* xcs = alloc(128 * 4096);
  float* dlt = alloc((size_t)4 * 128 * 4096);
  float* Bsb = alloc(4 * 16 * 4096);
  float* Csb = alloc(4 * 16 * 4096);
  float* ysb = alloc((size_t)4 * 128 * 4096);
  float* hloc = alloc(4 * 128 * 64 * 16);
  float* pAb = alloc(4 * 128 * 64 * 16);
  float* hin = alloc(4 * 128 * 64 * 16);
  float* sk0 = alloc(64 * 4096);
  float* sk1 = alloc(64 * 1024);
  float* sk2 = alloc(64 * 256);
  float* sk3 = alloc(64 * 64);
  float* tmpR = alloc((size_t)64 * 256 * 256);

  k_patch_embed<<<(64 * 4096 + 255) / 256, 256, 0, stream>>>(E0, pe_w, pe_b, xA);
  k_ln2d64<<<4096, 64, 0, stream>>>(xA, pe_lg, pe_lb, xB, 4096);
  float* x = xB;
  float* xalt = xA;

  int Hs[4] = {64, 32, 16, 8};
  int lgHs[4] = {6, 5, 4, 3};
  float* skips[4] = {sk0, sk1, sk2, sk3};
  int cur = 0;

  auto vss = [&](int H, int lgH) {
    int L = H * H;
    int nc = (L + CS - 1) / CS;
    k_lnproj<<<L, 256, 0, stream>>>(x, ln_g + cur * 64, ln_b + cur * 64,
                                    in_w + (size_t)cur * 64 * 256, xc, zb, L);
    k_dwconv<<<(128 * L + 255) / 256, 256, 0, stream>>>(xc, cv_w + (size_t)cur * 128 * 9,
                                                        cv_b + cur * 128, xcs, H, lgH);
    dim3 gx(L, 4);
    k_xproj<<<gx, 256, 0, stream>>>(xcs, xp_w + (size_t)cur * 4 * 36 * 128,
                                    dt_w + (size_t)cur * 4 * 128 * 4, dt_b + cur * 4 * 128,
                                    dlt, Bsb, Csb, H, lgH);
    dim3 ga(nc, 4);
    k_scanA<<<ga, 128, 0, stream>>>(xcs, dlt, Bsb, A_log + (size_t)cur * 4 * 128 * 16, hloc,
                                    pAb, H, lgH, nc);
    k_scanB<<<4, 128, 0, stream>>>(hloc, pAb, hin, nc);
    k_scanC<<<ga, 128, 0, stream>>>(xcs, dlt, Bsb, Csb, A_log + (size_t)cur * 4 * 128 * 16,
                                    Dp + cur * 4 * 128, hin, ysb, H, lgH, nc);
    k_combine<<<L, 128, 0, stream>>>(ysb, zb, x, on_g + cur * 128, on_b + cur * 128,
                                     out_pw + (size_t)cur * 128 * 64, xalt, H, lgH);
    std::swap(x, xalt);
    cur++;
  };

  for (int i = 0; i < 4; i++) {
    int H = Hs[i], lgH = lgHs[i];
    vss(H, lgH);
    vss(H, lgH);
    hipMemcpyAsync(skips[i], x, (size_t)64 * H * H * sizeof(float),
                   hipMemcpyDeviceToDevice, stream);
    if (i < 3) {
      int Ho = H / 2;
      k_conv3x3_s2<<<(64 * Ho * Ho + 255) / 256, 256, 0, stream>>>(
          x, dn_w + (size_t)i * 64 * 64 * 9, dn_b + i * 64, xalt, H, Ho);
      k_ln2d64<<<Ho * Ho, 64, 0, stream>>>(xalt, dn_g + i * 64, dn_lb + i * 64, x, Ho * Ho);
    }
  }

  // up path: x at 8x8
  for (int i = 0; i < 3; i++) {
    int Hin = 8 << i, Ho = Hin * 2;
    k_resize<<<(64 * Ho * Ho + 255) / 256, 256, 0, stream>>>(x, tmpR, Hin, Hin, Ho, Ho, 0.5f);
    dim3 g(Ho / 8, Ho / 8);
    k_conv3x3_s1<<<g, 256, 0, stream>>>(tmpR, up_w + (size_t)i * 64 * 64 * 9, up_b + i * 64,
                                        skips[2 - i], xalt, Ho, Ho, 1);
    std::swap(x, xalt);
  }

  // final: x at 64x64 -> resize x4 -> conv+silu -> out
  k_resize<<<(64 * 256 * 256 + 255) / 256, 256, 0, stream>>>(x, tmpR, 64, 64, 256, 256, 0.25f);
  dim3 gf(32, 32);
  k_conv3x3_s1<<<gf, 256, 0, stream>>>(tmpR, oc_w, oc_b, nullptr, (float*)d_out, 256, 256, 1);
}

// Round 3
// 1314.159 us; speedup vs baseline: 2.3475x; 1.3464x over previous
//
#include <hip/hip_runtime.h>
#include <hip/hip_bf16.h>
#include <utility>

#define CIC 8   // conv input-channel chunk

// ---------------- patch embed (conv4x4 s4) + ln2d64 fused; one wave per pixel
__global__ void k_patch_embed_ln(const float* __restrict__ E0, const float* __restrict__ w,
                                 const float* __restrict__ b, const float* __restrict__ g,
                                 const float* __restrict__ lb, float* __restrict__ out) {
  int p = blockIdx.x;
  int c = threadIdx.x;  // 64
  int oh = p >> 6, ow = p & 63;
  const float* src = E0 + (oh * 4) * 256 + ow * 4;
  const float* wc = w + c * 16;
  float acc = b[c];
#pragma unroll
  for (int i = 0; i < 4; i++)
#pragma unroll
    for (int j = 0; j < 4; j++) acc += src[i * 256 + j] * wc[i * 4 + j];
  float s = acc, s2 = acc * acc;
#pragma unroll
  for (int m = 32; m >= 1; m >>= 1) {
    s += __shfl_xor(s, m, 64);
    s2 += __shfl_xor(s2, m, 64);
  }
  float mu = s * (1.f / 64.f);
  float var = s2 * (1.f / 64.f) - mu * mu;
  float rstd = rsqrtf(var + 1e-6f);
  out[c * 4096 + p] = (acc - mu) * rstd * g[c] + lb[c];
}

// ---------------- ln2d over C=64 channels (one wave per pixel)
__global__ void k_ln2d64(const float* __restrict__ x, const float* __restrict__ g,
                         const float* __restrict__ b, float* __restrict__ y, int HW) {
  int p = blockIdx.x;
  int c = threadIdx.x;
  float v = x[c * HW + p];
  float s = v, s2 = v * v;
#pragma unroll
  for (int m = 32; m >= 1; m >>= 1) {
    s += __shfl_xor(s, m, 64);
    s2 += __shfl_xor(s2, m, 64);
  }
  float mu = s * (1.f / 64.f);
  float var = s2 * (1.f / 64.f) - mu * mu;
  float rstd = rsqrtf(var + 1e-6f);
  y[c * HW + p] = (v - mu) * rstd * g[c] + b[c];
}

// ---------------- fused ln2d(C=64) + input projection (64 -> 256), split xc/z
__global__ void k_lnproj(const float* __restrict__ x, const float* __restrict__ g,
                         const float* __restrict__ b, const float* __restrict__ w,
                         float* __restrict__ xc, float* __restrict__ z, int HW) {
  int p = blockIdx.x;
  int t = threadIdx.x;  // 256 threads
  __shared__ float hsh[64];
  if (t < 64) {
    float v = x[t * HW + p];
    float s = v, s2 = v * v;
#pragma unroll
    for (int m = 32; m >= 1; m >>= 1) {
      s += __shfl_xor(s, m, 64);
      s2 += __shfl_xor(s2, m, 64);
    }
    float mu = s * (1.f / 64.f);
    float var = s2 * (1.f / 64.f) - mu * mu;
    float rstd = rsqrtf(var + 1e-6f);
    hsh[t] = (v - mu) * rstd * g[t] + b[t];
  }
  __syncthreads();
  float acc = 0.f;
  const float* wp = w + t;  // w[c*256 + t]
#pragma unroll
  for (int c = 0; c < 64; c++) acc += hsh[c] * wp[c * 256];
  if (t < 128)
    xc[(size_t)p * 128 + t] = acc;
  else
    z[(size_t)p * 128 + (t - 128)] = acc;
}

// ---------------- depthwise conv 3x3 pad 1 + silu; pixel-major [L][128]
__global__ void k_dwconv(const float* __restrict__ xc, const float* __restrict__ w,
                         const float* __restrict__ b, float* __restrict__ out, int H, int lgH) {
  int HW = H * H;
  int idx = blockIdx.x * blockDim.x + threadIdx.x;
  if (idx >= 128 * HW) return;
  int p = idx >> 7;
  int d = idx & 127;
  int ph = p >> lgH, pw = p & (H - 1);
  const float* wp = w + d * 9;
  float acc = b[d];
#pragma unroll
  for (int i = 0; i < 3; i++) {
    int ih = ph + i - 1;
    if (ih < 0 || ih >= H) continue;
#pragma unroll
    for (int j = 0; j < 3; j++) {
      int iw = pw + j - 1;
      if (iw < 0 || iw >= H) continue;
      acc += xc[(size_t)(ih * H + iw) * 128 + d] * wp[i * 3 + j];
    }
  }
  out[(size_t)p * 128 + d] = acc / (1.f + __expf(-acc));
}

// ---------------- x-projection + delta=softplus(...)
// xcs: [L][128]; delta out: [k][L][128]; Bs/Cs out: [k][L][16]
__global__ void k_xproj(const float* __restrict__ xcs, const float* __restrict__ xpw,
                        const float* __restrict__ dtw, const float* __restrict__ dtb,
                        float* __restrict__ delta, float* __restrict__ Bs,
                        float* __restrict__ Cs, int H, int lgH) {
  int L = H * H;
  int l = blockIdx.x;
  int k = blockIdx.y;
  int t = threadIdx.x;  // 256
  int lm = (k & 2) ? (L - 1 - l) : l;
  int idx = (k & 1) ? ((lm & (H - 1)) * H + (lm >> lgH)) : lm;
  __shared__ float xs[128];
  __shared__ float part[36][4];
  __shared__ float r4[4];
  if (t < 128) xs[t] = xcs[(size_t)idx * 128 + t];
  __syncthreads();
  if (t < 144) {
    int r = t >> 2, q = t & 3;
    const float* wr = xpw + (k * 36 + r) * 128 + q * 32;
    const float* xp = xs + q * 32;
    float acc = 0.f;
#pragma unroll
    for (int c = 0; c < 32; c++) acc += xp[c] * wr[c];
    part[r][q] = acc;
  }
  __syncthreads();
  if (t < 36) {
    float acc = part[t][0] + part[t][1] + part[t][2] + part[t][3];
    if (t < 4)
      r4[t] = acc;
    else if (t < 20)
      Bs[((size_t)k * L + l) * 16 + (t - 4)] = acc;
    else
      Cs[((size_t)k * L + l) * 16 + (t - 20)] = acc;
  }
  __syncthreads();
  if (t < 128) {
    float dt = dtb[k * 128 + t];
    const float* wd = dtw + (k * 128 + t) * 4;
    dt += r4[0] * wd[0] + r4[1] * wd[1] + r4[2] * wd[2] + r4[3] * wd[3];
    float sp = fmaxf(dt, 0.f) + log1pf(__expf(-fabsf(dt)));
    delta[((size_t)k * L + l) * 128 + t] = sp;
  }
}

// ---------------- scan phase A: per-chunk local scan (init 0) + chunk decay
__global__ void k_scanA(const float* __restrict__ xcs, const float* __restrict__ delta,
                        const float* __restrict__ Bs, const float* __restrict__ A_log,
                        float* __restrict__ hloc, float* __restrict__ pA, int H, int lgH,
                        int nc, int cs) {
  int L = H * H;
  int c = blockIdx.x;
  int k = blockIdx.y;
  int d = threadIdx.x;  // 128
  float A[16], h[16];
#pragma unroll
  for (int n = 0; n < 16; n++) {
    A[n] = -expf(A_log[(k * 128 + d) * 16 + n]);
    h[n] = 0.f;
  }
  float sumdt = 0.f;
  int l0 = c * cs;
  for (int l = l0; l < l0 + cs; l++) {
    int lm = (k & 2) ? (L - 1 - l) : l;
    int idx = (k & 1) ? ((lm & (H - 1)) * H + (lm >> lgH)) : lm;
    float u = xcs[(size_t)idx * 128 + d];
    float dt = delta[((size_t)k * L + l) * 128 + d];
    float du = dt * u;
    sumdt += dt;
    const float4* bp = (const float4*)(Bs + ((size_t)k * L + l) * 16);
    float4 B0 = bp[0], B1 = bp[1], B2 = bp[2], B3 = bp[3];
    float Bv[16] = {B0.x, B0.y, B0.z, B0.w, B1.x, B1.y, B1.z, B1.w,
                    B2.x, B2.y, B2.z, B2.w, B3.x, B3.y, B3.z, B3.w};
#pragma unroll
    for (int n = 0; n < 16; n++) h[n] = __expf(dt * A[n]) * h[n] + Bv[n] * du;
  }
  size_t base = (((size_t)(k * 128 + d)) * nc + c) * 16;
#pragma unroll
  for (int n = 0; n < 16; n++) {
    hloc[base + n] = h[n];
    pA[base + n] = __expf(A[n] * sumdt);
  }
}

// ---------------- scan phase B: 8192 independent (k,d,n) recurrences over chunks
__global__ void k_scanB(const float* __restrict__ hloc, const float* __restrict__ pA,
                        float* __restrict__ hinit, int nc) {
  int tid = blockIdx.x * blockDim.x + threadIdx.x;  // 8192 total
  int k = tid >> 11;
  int d = (tid >> 4) & 127;
  int n = tid & 15;
  size_t rb = ((size_t)(k * 128 + d)) * nc * 16 + n;
  float h = 0.f;
  for (int c = 0; c < nc; c++) {
    size_t a = rb + (size_t)c * 16;
    hinit[a] = h;
    h = pA[a] * h + hloc[a];
  }
}

// ---------------- scan phase C: rescan with correct init, emit y; ys: [k][L][128]
__global__ void k_scanC(const float* __restrict__ xcs, const float* __restrict__ delta,
                        const float* __restrict__ Bs, const float* __restrict__ Cs,
                        const float* __restrict__ A_log, const float* __restrict__ Dp,
                        const float* __restrict__ hinit, float* __restrict__ ys, int H,
                        int lgH, int nc, int cs) {
  int L = H * H;
  int c = blockIdx.x;
  int k = blockIdx.y;
  int d = threadIdx.x;
  float A[16], h[16];
  size_t base = (((size_t)(k * 128 + d)) * nc + c) * 16;
#pragma unroll
  for (int n = 0; n < 16; n++) {
    A[n] = -expf(A_log[(k * 128 + d) * 16 + n]);
    h[n] = hinit[base + n];
  }
  float Dv = Dp[k * 128 + d];
  int l0 = c * cs;
  for (int l = l0; l < l0 + cs; l++) {
    int lm = (k & 2) ? (L - 1 - l) : l;
    int idx = (k & 1) ? ((lm & (H - 1)) * H + (lm >> lgH)) : lm;
    float u = xcs[(size_t)idx * 128 + d];
    float dt = delta[((size_t)k * L + l) * 128 + d];
    float du = dt * u;
    const float4* bp = (const float4*)(Bs + ((size_t)k * L + l) * 16);
    float4 B0 = bp[0], B1 = bp[1], B2 = bp[2], B3 = bp[3];
    float Bv[16] = {B0.x, B0.y, B0.z, B0.w, B1.x, B1.y, B1.z, B1.w,
                    B2.x, B2.y, B2.z, B2.w, B3.x, B3.y, B3.z, B3.w};
    const float4* cp = (const float4*)(Cs + ((size_t)k * L + l) * 16);
    float4 C0 = cp[0], C1 = cp[1], C2 = cp[2], C3 = cp[3];
    float Cv[16] = {C0.x, C0.y, C0.z, C0.w, C1.x, C1.y, C1.z, C1.w,
                    C2.x, C2.y, C2.z, C2.w, C3.x, C3.y, C3.z, C3.w};
    float y = 0.f;
#pragma unroll
    for (int n = 0; n < 16; n++) {
      h[n] = __expf(dt * A[n]) * h[n] + Bv[n] * du;
      y += h[n] * Cv[n];
    }
    ys[((size_t)k * L + l) * 128 + d] = y + Dv * u;
  }
}

// ---------------- combine 4 dirs + LN(128) + silu(z) gate + out proj + residual
__global__ void k_combine(const float* __restrict__ ys, const float* __restrict__ z,
                          const float* __restrict__ xin, const float* __restrict__ ong,
                          const float* __restrict__ onb, const float* __restrict__ outw,
                          float* __restrict__ xout, int H, int lgH) {
  int L = H * H;
  int p = blockIdx.x;
  int d = threadIdx.x;  // 128
  int ph = p >> lgH, pw = p & (H - 1);
  int l1 = pw * H + ph;
  float yv = ys[((size_t)0 * L + p) * 128 + d] + ys[((size_t)1 * L + l1) * 128 + d] +
             ys[((size_t)2 * L + (L - 1 - p)) * 128 + d] +
             ys[((size_t)3 * L + (L - 1 - l1)) * 128 + d];
  float s = yv, s2 = yv * yv;
#pragma unroll
  for (int m = 32; m >= 1; m >>= 1) {
    s += __shfl_xor(s, m, 64);
    s2 += __shfl_xor(s2, m, 64);
  }
  __shared__ float ws1[2], ws2[2];
  int wid = d >> 6;
  if ((d & 63) == 0) {
    ws1[wid] = s;
    ws2[wid] = s2;
  }
  __syncthreads();
  float tot = ws1[0] + ws1[1], tot2 = ws2[0] + ws2[1];
  float mu = tot * (1.f / 128.f);
  float var = tot2 * (1.f / 128.f) - mu * mu;
  float rstd = rsqrtf(var + 1e-6f);
  float zt = z[(size_t)p * 128 + d];
  float yt = ((yv - mu) * rstd * ong[d] + onb[d]) * (zt / (1.f + __expf(-zt)));
  __shared__ float ysm[128];
  ysm[d] = yt;
  __syncthreads();
  if (d < 64) {
    float acc = xin[(size_t)d * L + p];
#pragma unroll
    for (int q = 0; q < 128; q++) acc += ysm[q] * outw[q * 64 + d];
    xout[(size_t)d * L + p] = acc;
  }
}

// ---------------- naive per-output conv3x3 64->64 (stride 1 or 2, silu, skip)
__global__ void k_conv_naive(const float* __restrict__ x, const float* __restrict__ w,
                             const float* __restrict__ b, const float* __restrict__ skip,
                             float* __restrict__ out, int Hin, int Hout, int stride,
                             int do_silu) {
  int idx = blockIdx.x * blockDim.x + threadIdx.x;
  int HWo = Hout * Hout;
  if (idx >= 64 * HWo) return;
  int co = idx / HWo;
  int p = idx - co * HWo;
  int oh = p / Hout, ow = p - (p / Hout) * Hout;
  float acc = b[co];
  const float* wb = w + co * 64 * 9;
  for (int ci = 0; ci < 64; ci++) {
    const float* xb = x + (size_t)ci * Hin * Hin;
    const float* wc = wb + ci * 9;
#pragma unroll
    for (int i = 0; i < 3; i++) {
      int ih = oh * stride + i - 1;
      if (ih < 0 || ih >= Hin) continue;
#pragma unroll
      for (int j = 0; j < 3; j++) {
        int iw = ow * stride + j - 1;
        if (iw < 0 || iw >= Hin) continue;
        acc += xb[ih * Hin + iw] * wc[i * 3 + j];
      }
    }
  }
  if (do_silu) acc = acc / (1.f + __expf(-acc));
  if (skip) acc += skip[idx];
  out[idx] = acc;
}

// ---------------- register-blocked tiled conv3x3 s1: 16x16 tile, thread=2x2 px x 16 co
__global__ void __launch_bounds__(256) k_conv16(const float* __restrict__ x,
                                                const float* __restrict__ w,
                                                const float* __restrict__ b,
                                                float* __restrict__ out, int H, int W,
                                                int do_silu) {
  __shared__ __align__(16) float xsh[CIC][18][18];
  __shared__ __align__(16) float wsh[CIC][64][12];
  int t = threadIdx.x;
  int q = t & 63, cog = t >> 6;
  int qx = q & 7, qy = q >> 3;
  int ox = blockIdx.x * 16, oy = blockIdx.y * 16;
  float acc[4][16];
#pragma unroll
  for (int pp = 0; pp < 4; pp++)
#pragma unroll
    for (int i = 0; i < 16; i++) acc[pp][i] = 0.f;
  for (int cb = 0; cb < 64; cb += CIC) {
    for (int i = t; i < CIC * 324; i += 256) {
      int ci = i / 324;
      int r = i - ci * 324;
      int iy = r / 18, ix = r - (r / 18) * 18;
      int gy = oy + iy - 1, gx = ox + ix - 1;
      float v = 0.f;
      if (gy >= 0 && gy < H && gx >= 0 && gx < W) v = x[(size_t)(cb + ci) * H * W + gy * W + gx];
      xsh[ci][iy][ix] = v;
    }
    for (int i = t; i < CIC * 576; i += 256) {
      int ci = i / 576;
      int r = i - ci * 576;
      int co = r / 9, tap = r - (r / 9) * 9;
      wsh[ci][co][tap] = w[(size_t)co * 576 + (cb + ci) * 9 + tap];
    }
    __syncthreads();
#pragma unroll
    for (int ci = 0; ci < CIC; ci++) {
      float xv[4][4];
#pragma unroll
      for (int r = 0; r < 4; r++) {
        float2 a = *(const float2*)&xsh[ci][2 * qy + r][2 * qx];
        float2 bq = *(const float2*)&xsh[ci][2 * qy + r][2 * qx + 2];
        xv[r][0] = a.x;
        xv[r][1] = a.y;
        xv[r][2] = bq.x;
        xv[r][3] = bq.y;
      }
#pragma unroll
      for (int i = 0; i < 16; i++) {
        int co = cog * 16 + i;
        float4 w0 = *(const float4*)&wsh[ci][co][0];
        float4 w1 = *(const float4*)&wsh[ci][co][4];
        float w8 = wsh[ci][co][8];
#pragma unroll
        for (int dy = 0; dy < 2; dy++)
#pragma unroll
          for (int dx = 0; dx < 2; dx++) {
            float* a = acc[dy * 2 + dx];
            a[i] += xv[dy + 0][dx + 0] * w0.x + xv[dy + 0][dx + 1] * w0.y +
                    xv[dy + 0][dx + 2] * w0.z + xv[dy + 1][dx + 0] * w0.w +
                    xv[dy + 1][dx + 1] * w1.x + xv[dy + 1][dx + 2] * w1.y +
                    xv[dy + 2][dx + 0] * w1.z + xv[dy + 2][dx + 1] * w1.w +
                    xv[dy + 2][dx + 2] * w8;
          }
      }
    }
    __syncthreads();
  }
#pragma unroll
  for (int dy = 0; dy < 2; dy++)
#pragma unroll
    for (int dx = 0; dx < 2; dx++) {
      int gy = oy + 2 * qy + dy, gx = ox + 2 * qx + dx;
#pragma unroll
      for (int i = 0; i < 16; i++) {
        float a = acc[dy * 2 + dx][i] + b[cog * 16 + i];
        if (do_silu) a = a / (1.f + __expf(-a));
        out[(size_t)(cog * 16 + i) * H * W + gy * W + gx] = a;
      }
    }
}

// ---------------- bilinear resize (half-pixel centers, edge clamp)
__global__ void k_resize(const float* __restrict__ x, float* __restrict__ out, int Hin,
                         int Win, int Hout, int Wout, float inv_scale) {
  int idx = blockIdx.x * blockDim.x + threadIdx.x;
  int HWo = Hout * Wout;
  if (idx >= 64 * HWo) return;
  int c = idx / HWo;
  int p = idx - c * HWo;
  int oh = p / Wout, ow = p - (p / Wout) * Wout;
  float sh = (oh + 0.5f) * inv_scale - 0.5f;
  float sw = (ow + 0.5f) * inv_scale - 0.5f;
  int h0 = (int)floorf(sh);
  float fh = sh - h0;
  int w0 = (int)floorf(sw);
  float fw = sw - w0;
  int h0c = min(max(h0, 0), Hin - 1), h1c = min(max(h0 + 1, 0), Hin - 1);
  int w0c = min(max(w0, 0), Win - 1), w1c = min(max(w0 + 1, 0), Win - 1);
  const float* xb = x + (size_t)c * Hin * Win;
  float v = (1.f - fh) * ((1.f - fw) * xb[h0c * Win + w0c] + fw * xb[h0c * Win + w1c]) +
            fh * ((1.f - fw) * xb[h1c * Win + w0c] + fw * xb[h1c * Win + w1c]);
  out[idx] = v;
}

extern "C" void kernel_launch(void* const* d_in, const int* in_sizes, int n_in, void* d_out,
                              int out_size, void* d_ws, size_t ws_size, hipStream_t stream) {
  const float* E0 = (const float*)d_in[0];
  const float* pe_w = (const float*)d_in[1];
  const float* pe_b = (const float*)d_in[2];
  const float* pe_lg = (const float*)d_in[3];
  const float* pe_lb = (const float*)d_in[4];
  const float* ln_g = (const float*)d_in[5];
  const float* ln_b = (const float*)d_in[6];
  const float* in_w = (const float*)d_in[7];
  const float* cv_w = (const float*)d_in[8];
  const float* cv_b = (const float*)d_in[9];
  const float* xp_w = (const float*)d_in[10];
  const float* dt_w = (const float*)d_in[11];
  const float* dt_b = (const float*)d_in[12];
  const float* A_log = (const float*)d_in[13];
  const float* Dp = (const float*)d_in[14];
  const float* on_g = (const float*)d_in[15];
  const float* on_b = (const float*)d_in[16];
  const float* out_pw = (const float*)d_in[17];
  const float* dn_w = (const float*)d_in[18];
  const float* dn_b = (const float*)d_in[19];
  const float* dn_g = (const float*)d_in[20];
  const float* dn_lb = (const float*)d_in[21];
  const float* up_w = (const float*)d_in[22];
  const float* up_b = (const float*)d_in[23];
  const float* oc_w = (const float*)d_in[24];
  const float* oc_b = (const float*)d_in[25];

  float* ws = (float*)d_ws;
  size_t off = 0;
  auto alloc = [&](size_t n) {
    float* p = ws + off;
    off += n;
    return p;
  };
  float* xA = alloc(64 * 4096);
  float* xB = alloc(64 * 4096);
  float* xc = alloc(128 * 4096);
  float* zb = alloc(128 * 4096);
  float* xcs = alloc(128 * 4096);
  float* dlt = alloc((size_t)4 * 128 * 4096);
  float* Bsb = alloc(4 * 16 * 4096);
  float* Csb = alloc(4 * 16 * 4096);
  float* ysb = alloc((size_t)4 * 128 * 4096);
  float* hloc = alloc((size_t)4 * 128 * 128 * 16);
  float* pAb = alloc((size_t)4 * 128 * 128 * 16);
  float* hin = alloc((size_t)4 * 128 * 128 * 16);
  float* sk0 = alloc(64 * 4096);
  float* sk1 = alloc(64 * 1024);
  float* sk2 = alloc(64 * 256);
  float* sk3 = alloc(64 * 64);
  float* tmpR = alloc((size_t)64 * 256 * 256);

  k_patch_embed_ln<<<4096, 64, 0, stream>>>(E0, pe_w, pe_b, pe_lg, pe_lb, xB);
  float* x = xB;
  float* xalt = xA;

  int Hs[4] = {64, 32, 16, 8};
  int lgHs[4] = {6, 5, 4, 3};
  int CSs[4] = {32, 16, 8, 8};
  float* skips[4] = {sk0, sk1, sk2, sk3};
  int cur = 0;

  auto vss = [&](int H, int lgH, int cs) {
    int L = H * H;
    int nc = L / cs;
    k_lnproj<<<L, 256, 0, stream>>>(x, ln_g + cur * 64, ln_b + cur * 64,
                                    in_w + (size_t)cur * 64 * 256, xc, zb, L);
    k_dwconv<<<(128 * L + 255) / 256, 256, 0, stream>>>(xc, cv_w + (size_t)cur * 128 * 9,
                                                        cv_b + cur * 128, xcs, H, lgH);
    dim3 gx(L, 4);
    k_xproj<<<gx, 256, 0, stream>>>(xcs, xp_w + (size_t)cur * 4 * 36 * 128,
                                    dt_w + (size_t)cur * 4 * 128 * 4, dt_b + cur * 4 * 128,
                                    dlt, Bsb, Csb, H, lgH);
    dim3 ga(nc, 4);
    k_scanA<<<ga, 128, 0, stream>>>(xcs, dlt, Bsb, A_log + (size_t)cur * 4 * 128 * 16, hloc,
                                    pAb, H, lgH, nc, cs);
    k_scanB<<<32, 256, 0, stream>>>(hloc, pAb, hin, nc);
    k_scanC<<<ga, 128, 0, stream>>>(xcs, dlt, Bsb, Csb, A_log + (size_t)cur * 4 * 128 * 16,
                                    Dp + cur * 4 * 128, hin, ysb, H, lgH, nc, cs);
    k_combine<<<L, 128, 0, stream>>>(ysb, zb, x, on_g + cur * 128, on_b + cur * 128,
                                     out_pw + (size_t)cur * 128 * 64, xalt, H, lgH);
    std::swap(x, xalt);
    cur++;
  };

  for (int i = 0; i < 4; i++) {
    int H = Hs[i], lgH = lgHs[i];
    vss(H, lgH, CSs[i]);
    vss(H, lgH, CSs[i]);
    hipMemcpyAsync(skips[i], x, (size_t)64 * H * H * sizeof(float),
                   hipMemcpyDeviceToDevice, stream);
    if (i < 3) {
      int Ho = H / 2;
      k_conv_naive<<<(64 * Ho * Ho + 255) / 256, 256, 0, stream>>>(
          x, dn_w + (size_t)i * 64 * 64 * 9, dn_b + i * 64, nullptr, xalt, H, Ho, 2, 0);
      k_ln2d64<<<Ho * Ho, 64, 0, stream>>>(xalt, dn_g + i * 64, dn_lb + i * 64, x, Ho * Ho);
    }
  }

  // up path: x at 8x8
  for (int i = 0; i < 3; i++) {
    int Hin = 8 << i, Ho = Hin * 2;
    k_resize<<<(64 * Ho * Ho + 255) / 256, 256, 0, stream>>>(x, tmpR, Hin, Hin, Ho, Ho, 0.5f);
    k_conv_naive<<<(64 * Ho * Ho + 255) / 256, 256, 0, stream>>>(
        tmpR, up_w + (size_t)i * 64 * 64 * 9, up_b + i * 64, skips[2 - i], xalt, Ho, Ho, 1, 1);
    std::swap(x, xalt);
  }

  // final: x at 64x64 -> resize x4 -> conv+silu -> out
  k_resize<<<(64 * 256 * 256 + 255) / 256, 256, 0, stream>>>(x, tmpR, 64, 64, 256, 256, 0.25f);
  dim3 gf(16, 16);
  k_conv16<<<gf, 256, 0, stream>>>(tmpR, oc_w, oc_b, (float*)d_out, 256, 256, 1);
}